// Round 1
// 223.245 us; speedup vs baseline: 1.0322x; 1.0322x over previous
//
#include <hip/hip_runtime.h>
#include <hip/hip_bf16.h>

// ---- types ------------------------------------------------------------
typedef short short8 __attribute__((ext_vector_type(8)));   // 8 bf16 MFMA A/B frag
typedef float f32x4  __attribute__((ext_vector_type(4)));   // MFMA C/D frag (16x16)
typedef float f32x16 __attribute__((ext_vector_type(16)));  // MFMA C/D frag (32x32)
typedef unsigned int u32x4 __attribute__((ext_vector_type(4))); // 16B vehicle

union V16   { u32x4 v; short8 s; };
union U16x8 { u32x4 v; unsigned short u[8]; };
union FB4   { u32x4 v; float f[4]; };
union BF2U  { __hip_bfloat162 h; unsigned int u; };

__device__ inline unsigned short f2bf(float f) {
  union { float f; unsigned int u; } x; x.f = f;
  unsigned int u = x.u + 0x7fffu + ((x.u >> 16) & 1u);   // RNE
  return (unsigned short)(u >> 16);
}

__device__ __forceinline__ unsigned int pkbf(float a, float b) {
  BF2U p; p.h = __float22bfloat162_rn(make_float2(a, b)); return p.u;
}

// v_permlane32_swap_b32: a'[0:31]=a[0:31], a'[32:63]=b[0:31],
//                        b'[0:31]=a[32:63], b'[32:63]=b[32:63]
__device__ __forceinline__ void plswap(unsigned int& a, unsigned int& b) {
  asm("v_permlane32_swap_b32 %0, %1" : "+v"(a), "+v"(b));
}

// fp32-vs-bf16 input detection from hs's first 64 even u16 words
__device__ __forceinline__ int probe_fp32(const unsigned short* hs) {
  int bad = 0;
#pragma unroll
  for (int i = 0; i < 64; ++i) {
    unsigned int e = (hs[2 * i] >> 7) & 0xFFu;
    if (e >= 0xFEu || (e > 0u && e < 0x60u)) bad++;
  }
  return bad >= 6;
}

// async global->LDS DMA, 16B/lane; LDS dest = wave-uniform base + lane*16
__device__ __forceinline__ void gl_lds16(const unsigned short* g, unsigned short* l) {
  __builtin_amdgcn_global_load_lds(
      (const __attribute__((address_space(1))) unsigned int*)g,
      (__attribute__((address_space(3))) unsigned int*)l, 16, 0, 0);
}

// ---- weights transpose (z=0..3) + hs convert (z=4), one dispatch ------
// z=0: Wq->WT[0:192), z=1: Wk->WT[192:384), z=2: Wv->WT[384:1920), z=3: Wo->WoT
// z=4: hs -> hsb (bf16 contiguous), block idx = y*48+x, 2048 el/block
__global__ __launch_bounds__(256) void w_tr(const void* __restrict__ Wq,
                                            const void* __restrict__ Wk,
                                            const void* __restrict__ Wv,
                                            const void* __restrict__ Wo,
                                            const void* __restrict__ hs,
                                            unsigned short* __restrict__ WT,
                                            unsigned short* __restrict__ WoT,
                                            unsigned short* __restrict__ hsb) {
  __shared__ unsigned short t[32][33];
  __shared__ int sf;
  if (threadIdx.x == 0) sf = probe_fp32((const unsigned short*)hs);
  __syncthreads();
  const int f = sf;
  const int z = blockIdx.z;
  if (z == 4) {                            // hs convert path
    size_t i0 = ((size_t)(blockIdx.y * 48 + blockIdx.x) * 256 + threadIdx.x) * 8;
    if (f) {
      const float* in = (const float*)hs;
      FB4 a, b; a.v = *(const u32x4*)&in[i0]; b.v = *(const u32x4*)&in[i0 + 4];
      U16x8 p;
#pragma unroll
      for (int j = 0; j < 4; ++j) { p.u[j] = f2bf(a.f[j]); p.u[j + 4] = f2bf(b.f[j]); }
      *(u32x4*)&hsb[i0] = p.v;
    } else {
      *(u32x4*)&hsb[i0] = *(const u32x4*)((const unsigned short*)hs + i0);
    }
    return;
  }
  if (blockIdx.y >= 48) return;            // transpose paths: 48x48 grid
  const void* in_; unsigned short* out; int C;
  if      (z == 0) { in_ = Wq; out = WT;              C = 192;  }
  else if (z == 1) { in_ = Wk; out = WT + 192 * 1536; C = 192;  }
  else if (z == 2) { in_ = Wv; out = WT + 384 * 1536; C = 1536; }
  else             { in_ = Wo; out = WoT;             C = 1536; }
  const int c0 = blockIdx.x * 32;
  if (c0 >= C) return;                     // uniform early exit
  const int tx = threadIdx.x & 31, ty = threadIdx.x >> 5;
  const int r0 = blockIdx.y * 32;          // R = 1536 rows for all four
#pragma unroll
  for (int i = 0; i < 4; ++i) {
    size_t idx = (size_t)(r0 + ty + 8 * i) * C + (c0 + tx);
    t[ty + 8 * i][tx] = f ? f2bf(((const float*)in_)[idx])
                          : ((const unsigned short*)in_)[idx];
  }
  __syncthreads();
#pragma unroll
  for (int i = 0; i < 4; ++i)
    out[(size_t)(c0 + ty + 8 * i) * 1536 + (r0 + tx)] = t[tx][ty + 8 * i];
}

// ---- v transpose: out[z][c][r] = in[z][r][c] (internal bf16) ----------
__global__ __launch_bounds__(256) void tr_v(const unsigned short* __restrict__ in_,
                                            unsigned short* __restrict__ out,
                                            int R, int C, int ldin,
                                            long long in_bstride, long long out_bstride) {
  __shared__ unsigned short t[32][33];
  const size_t ibase = (size_t)blockIdx.z * in_bstride;
  const size_t obase = (size_t)blockIdx.z * out_bstride;
  const int tx = threadIdx.x & 31, ty = threadIdx.x >> 5;
  const int r0 = blockIdx.y * 32, c0 = blockIdx.x * 32;
#pragma unroll
  for (int i = 0; i < 4; ++i)
    t[ty + 8 * i][tx] = in_[ibase + (size_t)(r0 + ty + 8 * i) * ldin + (c0 + tx)];
  __syncthreads();
#pragma unroll
  for (int i = 0; i < 4; ++i)
    out[obase + (size_t)(c0 + ty + 8 * i) * R + (r0 + tx)] = t[tx][ty + 8 * i];
}

// ---- C[M][N] = A[M][K] @ BT[N][K]^T, A/BT bf16 ------------------------
// (unchanged proven Round-10 kernel: BK=64 double-buffered global_load_lds,
//  unpadded 128x64 tiles, global-side XOR swizzle, frag-probe swizzle)
__global__ __launch_bounds__(256) void gemm_bt(const unsigned short* __restrict__ A,
                                               const unsigned short* __restrict__ BT,
                                               void* __restrict__ C_,
                                               int M, int N, int K,
                                               const unsigned short* __restrict__ probe_src) {
  __shared__ unsigned short As[2][128][64];
  __shared__ unsigned short Bs[2][128][64];
  const int m0 = blockIdx.y * 128, n0 = blockIdx.x * 128;
  const int tid = threadIdx.x;
  const int lane = tid & 63, w = tid >> 6;
  const int wr = w >> 1, wc = w & 1;
  const int quad = lane >> 4, mrow = lane & 15;

  const int sr = lane >> 3;                          // staging row-in-8
  const int sc = ((lane & 7) ^ (lane >> 3)) * 8;     // swizzled global chunk (shorts)
  const int fsw = (mrow & 7);                        // frag-read swizzle

  const f32x4 zf = {0.f, 0.f, 0.f, 0.f};
  f32x4 acc[4][4];
#pragma unroll
  for (int mt = 0; mt < 4; ++mt)
#pragma unroll
    for (int nt = 0; nt < 4; ++nt) acc[mt][nt] = zf;

  const int nk = K >> 6;                             // BK=64 steps
#pragma unroll
  for (int j = 0; j < 4; ++j) {
    const int r = 32 * w + 8 * j + sr;
    gl_lds16(&A [(size_t)(m0 + r) * K + sc], &As[0][32 * w + 8 * j][0]);
    gl_lds16(&BT[(size_t)(n0 + r) * K + sc], &Bs[0][32 * w + 8 * j][0]);
  }

  for (int ks = 0; ks < nk; ++ks) {
    const int cur = ks & 1;
    __syncthreads();   // drains DMA for buf[cur]; prior reads of buf[cur^1] done
    if (ks + 1 < nk) {
      const int k1 = (ks + 1) << 6;
#pragma unroll
      for (int j = 0; j < 4; ++j) {
        const int r = 32 * w + 8 * j + sr;
        gl_lds16(&A [(size_t)(m0 + r) * K + k1 + sc], &As[cur ^ 1][32 * w + 8 * j][0]);
        gl_lds16(&BT[(size_t)(n0 + r) * K + k1 + sc], &Bs[cur ^ 1][32 * w + 8 * j][0]);
      }
    }
#pragma unroll
    for (int kq = 0; kq < 2; ++kq) {
      short8 afr[4], bfr[4];
#pragma unroll
      for (int mt = 0; mt < 4; ++mt) {
        V16 u; u.v = *(const u32x4*)&As[cur][wr * 64 + mt * 16 + mrow][((kq * 4 + quad) ^ fsw) * 8];
        afr[mt] = u.s;
      }
#pragma unroll
      for (int nt = 0; nt < 4; ++nt) {
        V16 u; u.v = *(const u32x4*)&Bs[cur][wc * 64 + nt * 16 + mrow][((kq * 4 + quad) ^ fsw) * 8];
        bfr[nt] = u.s;
      }
#pragma unroll
      for (int mt = 0; mt < 4; ++mt)
#pragma unroll
        for (int nt = 0; nt < 4; ++nt)
          acc[mt][nt] = __builtin_amdgcn_mfma_f32_16x16x32_bf16(afr[mt], bfr[nt], acc[mt][nt], 0, 0, 0);
    }
  }

  const int of = probe_src ? probe_fp32(probe_src) : 0;
#pragma unroll
  for (int mt = 0; mt < 4; ++mt)
#pragma unroll
    for (int nt = 0; nt < 4; ++nt)
#pragma unroll
      for (int r = 0; r < 4; ++r) {
        int grow = m0 + wr * 64 + mt * 16 + quad * 4 + r;
        int gcol = n0 + wc * 64 + nt * 16 + mrow;
        size_t idx = (size_t)grow * N + gcol;
        if (of) ((float*)C_)[idx] = acc[mt][nt][r];
        else    ((unsigned short*)C_)[idx] = f2bf(acc[mt][nt][r]);
      }
}

// ---- fused causal "based" attention — 32x32 swapped-QK^T rebuild -------
// Round-11: replace the 16x16 structure (half-K-wasted S MFMAs + 16 shfl
// transposes + 4x LDS read amplification) with the T12 form:
//   * wave owns 32 q rows; S^T = ONE mfma_f32_32x32x16_bf16 (K=16 exact)
//   * S^T C/D layout has col = lane&31 = q  ->  z is lane-local adds
//   * P -> PV A-frag = 8 cvt_pk + 4 v_permlane32_swap (pure VALU, no LDS)
//   * PV = 8 mfma_f32_32x32x16 per 32x32 P tile (25% more FLOP/cyc)
//   * 4 waves = 2 q-subtiles x 2 kv-parities over the shared V tile
//     (halves LDS read amplification; keeps the balanced 768-block grid);
//     kv-parity partials combined through LDS in the epilogue.
// qkv: [4096][1920] bf16 (cols 0..191 q, 192..383 k); vT: [24*128][2048]
// obuf: [4096][1536]. grid (24,32): (b*12+h, q-tile of 64). 256 threads.
__global__ __launch_bounds__(256, 3) void attn_based(const unsigned short* __restrict__ qkv,
                                                     const unsigned short* __restrict__ vT,
                                                     unsigned short* __restrict__ obuf) {
  __shared__ unsigned short Vs[2][128][64];  // [buf][hd][kv] bf16, 32 KB (DMA dest)
  __shared__ float zbuf[2][32];
  const int LD = 1920;
  const int bh = blockIdx.x;
  const int qt = 31 - blockIdx.y;            // long blocks dispatch first (LPT)
  const int b = bh / 12, h = bh % 12;
  const int tid = threadIdx.x;
  const int lane = tid & 63, w = tid >> 6;
  const int qsub = w & 1, kvp = w >> 1;      // q-subtile / kv-parity of this wave
  const int col = lane & 31, hi = lane >> 5;

  const int q0 = qt * 64 + qsub * 32;        // wave's q block start (abs)
  const int q_abs = q0 + col;

  // Q B-frag (loop-invariant): B[k=f][n=q]: lane holds q=col, f=hi*8+j
  V16 bq; bq.v = *(const u32x4*)&qkv[(size_t)(b * 2048 + q_abs) * LD + h * 16 + hi * 8];

  // K A-frag: A[m=kv][k=f]: lane holds kv=col (+kv0), f=hi*8+j
  const unsigned short* kptr =
      &qkv[(size_t)(b * 2048 + kvp * 32 + col) * LD + 192 + h * 16 + hi * 8];

  const unsigned short* vbase = vT + (size_t)(bh * 128) * 2048;

  const f32x16 z16 = {0.f,0.f,0.f,0.f,0.f,0.f,0.f,0.f,0.f,0.f,0.f,0.f,0.f,0.f,0.f,0.f};
  f32x16 oacc[4];                            // [hd-chunk of 32]
#pragma unroll
  for (int nc = 0; nc < 4; ++nc) oacc[nc] = z16;
  float zcA[4] = {0.f, 0.f, 0.f, 0.f};       // split z chains (merged at end)

  // V staging: tile t = vT[hd 0..127][t*64 .. t*64+63] -> Vs[buf][hd][kv],
  // global-side XOR swizzle (chunk ^ row&7) so frag reads are conflict-free.
#define STAGE_V(KV0, BUF)                                                     \
  {                                                                           \
    _Pragma("unroll")                                                         \
    for (int j = 0; j < 4; ++j) {                                             \
      const int row = 32 * w + 8 * j + (lane >> 3);                           \
      gl_lds16(vbase + (size_t)row * 2048 + (KV0) + ((lane & 7) ^ (lane >> 3)) * 8, \
               &Vs[BUF][32 * w + 8 * j][0]);                                  \
    }                                                                         \
  }

  STAGE_V(0, 0);
  V16 kf; kf.v = *(const u32x4*)kptr;        // K frag for tile 0
  __syncthreads();

  for (int t = 0; t <= qt; ++t) {
    const int cur = t & 1;
    if (t < qt) STAGE_V((t + 1) * 64, cur ^ 1);

    V16 kfn;
    kptr += (size_t)64 * LD;
    if (t < qt) kfn.v = *(const u32x4*)kptr;   // prefetch next K frag

    // wave-uniform: does this wave's kv sub-block exist under the causal mask?
    const bool live = (t < qt) | (kvp <= qsub);
    if (live) {
      // S^T[kv][q] in one MFMA: col = lane&31 = q, row kv = (r&3)+8*(r>>2)+4*hi
      f32x16 st = __builtin_amdgcn_mfma_f32_32x32x16_bf16(kf.s, bq.s, z16, 0, 0, 0);
      const int kv0 = t * 64 + kvp * 32;
      const bool diag = (t == qt) & (kvp == qsub);
      float pr[16];
      if (diag) {
#pragma unroll
        for (int r = 0; r < 16; ++r) {
          float s = st[r];
          float a = fmaf(s, fmaf(s, 0.03125f, 0.25f), 1.0f);
          const int kvr = kv0 + (r & 3) + 8 * (r >> 2) + 4 * hi;
          a = (kvr <= q_abs) ? a : 0.0f;
          zcA[r & 3] += a; pr[r] = a;
        }
      } else {
#pragma unroll
        for (int r = 0; r < 16; ++r) {
          float s = st[r];
          float a = fmaf(s, fmaf(s, 0.03125f, 0.25f), 1.0f);
          zcA[r & 3] += a; pr[r] = a;
        }
      }

      // P -> two PV A-frags (kv 0..15 / 16..31) via cvt_pk + permlane32_swap
      union PA { short8 s; unsigned int wd[4]; } pa0, pa1;
      {
        unsigned int x0 = pkbf(pr[0], pr[1]), x1 = pkbf(pr[2], pr[3]);
        unsigned int y0 = pkbf(pr[4], pr[5]), y1 = pkbf(pr[6], pr[7]);
        plswap(x0, y0); plswap(x1, y1);
        pa0.wd[0] = x0; pa0.wd[1] = x1; pa0.wd[2] = y0; pa0.wd[3] = y1;
      }
      {
        unsigned int x0 = pkbf(pr[8], pr[9]),  x1 = pkbf(pr[10], pr[11]);
        unsigned int y0 = pkbf(pr[12], pr[13]), y1 = pkbf(pr[14], pr[15]);
        plswap(x0, y0); plswap(x1, y1);
        pa1.wd[0] = x0; pa1.wd[1] = x1; pa1.wd[2] = y0; pa1.wd[3] = y1;
      }

      // PV: B[k=kv][n=hd] frags from swizzled Vs; 8 MFMAs, 2 chained per nc
      __builtin_amdgcn_s_setprio(1);
#pragma unroll
      for (int nc = 0; nc < 4; ++nc) {
        const int hd = nc * 32 + col;
        V16 v0, v1;
        v0.v = *(const u32x4*)&Vs[cur][hd][(((kvp * 4 + hi)     ^ (hd & 7)) * 8)];
        v1.v = *(const u32x4*)&Vs[cur][hd][(((kvp * 4 + 2 + hi) ^ (hd & 7)) * 8)];
        oacc[nc] = __builtin_amdgcn_mfma_f32_32x32x16_bf16(pa0.s, v0.s, oacc[nc], 0, 0, 0);
        oacc[nc] = __builtin_amdgcn_mfma_f32_32x32x16_bf16(pa1.s, v1.s, oacc[nc], 0, 0, 0);
      }
      __builtin_amdgcn_s_setprio(0);
    }
    __syncthreads();   // drains DMA (vmcnt) + guards buffer reuse
    if (t < qt) kf = kfn;
  }

  // z: merge split chains, then lane + lane^32 (rows 4..7 offset half)
  float zcol = (zcA[0] + zcA[1]) + (zcA[2] + zcA[3]);
  zcol += __shfl_xor(zcol, 32, 64);

  // combine kv-parity partials: waves 2,3 donate through LDS (reuse Vs)
  float* fbuf = (float*)&Vs[0][0][0];        // 8192 floats = 32 KB
  if (w >= 2) {
    const int base = (w & 1) * 4096;
#pragma unroll
    for (int nc = 0; nc < 4; ++nc)
#pragma unroll
      for (int g = 0; g < 4; ++g) {
        f32x4 v = {oacc[nc][4 * g], oacc[nc][4 * g + 1],
                   oacc[nc][4 * g + 2], oacc[nc][4 * g + 3]};
        *(f32x4*)&fbuf[base + ((nc * 4 + g) * 64 + lane) * 4] = v;
      }
    if (lane < 32) zbuf[w & 1][lane] = zcol;
  }
  __syncthreads();
  if (w < 2) {
    const int base = w * 4096;
#pragma unroll
    for (int nc = 0; nc < 4; ++nc)
#pragma unroll
      for (int g = 0; g < 4; ++g) {
        f32x4 v = *(const f32x4*)&fbuf[base + ((nc * 4 + g) * 64 + lane) * 4];
#pragma unroll
        for (int r = 0; r < 4; ++r) oacc[nc][4 * g + r] += v[r];
      }
    const float zinv = 1.0f / (zcol + zbuf[w][col] + 1e-12f);
    // D[q][hd]: col = lane&31 = hd-offset, row q = (r&3)+8*(r>>2)+4*hi
#pragma unroll
    for (int g = 0; g < 4; ++g)
#pragma unroll
      for (int rr = 0; rr < 4; ++rr) {
        const int qrow = rr + 8 * g + 4 * hi;
        const float iv = __shfl(zinv, qrow, 64);
        const size_t base_o = (size_t)(b * 2048 + q0 + qrow) * 1536 + h * 128 + col;
#pragma unroll
        for (int nc = 0; nc < 4; ++nc)
          obuf[base_o + nc * 32] = f2bf(oacc[nc][4 * g + rr] * iv);
      }
  }
#undef STAGE_V
}

// ---- launch -----------------------------------------------------------
extern "C" void kernel_launch(void* const* d_in, const int* in_sizes, int n_in,
                              void* d_out, int out_size, void* d_ws, size_t ws_size,
                              hipStream_t stream) {
  const void* hs = d_in[0];
  const void* Wq = d_in[1];
  const void* Wk = d_in[2];
  const void* Wv = d_in[3];
  const void* Wo = d_in[4];
  const unsigned short* hsp = (const unsigned short*)hs;

  // ws (~51.5 MB): WT[1920][1536] | WoT[1536][1536] | qkvb[4096][1920]
  //                | hsb[4096][1536] | vT[24*128][2048]
  unsigned short* ws   = (unsigned short*)d_ws;
  unsigned short* WT   = ws;                        // q 0..191, k 192..383, v 384..1919
  unsigned short* WoT  = WT + 1920 * 1536;
  unsigned short* qkvb = WoT + 1536 * 1536;
  unsigned short* hsb  = qkvb + 4096 * 1920;
  unsigned short* vT   = hsb + 4096 * 1536;
  unsigned short* obuf = hsb;                       // hsb dead after qkv gemm

  // weights transpose + hs convert, one dispatch
  w_tr<<<dim3(48, 64, 5), 256, 0, stream>>>(Wq, Wk, Wv, Wo, hs, WT, WoT, hsb);

  // fused q|k|v projection: [4096][1536] @ WT^T -> qkvb [4096][1920]
  gemm_bt<<<dim3(15, 32, 1), 256, 0, stream>>>(hsb, WT, qkvb, 4096, 1920, 1536, nullptr);

  // v columns of qkvb -> per-(b,h) [hd][l]
  tr_v<<<dim3(48, 64, 2), 256, 0, stream>>>(qkvb + 384, vT, 2048, 1536, 1920,
                                            (long long)2048 * 1920, (long long)1536 * 2048);

  // fused causal based-attention (32x32 swapped-QK^T, kv-parity split)
  attn_based<<<dim3(24, 32, 1), 256, 0, stream>>>(qkvb, vT, obuf);

  // output projection -> d_out (fp32 store iff inputs were fp32)
  gemm_bt<<<dim3(12, 32, 1), 256, 0, stream>>>(obuf, WoT, d_out, 4096, 1536, 1536, hsp);
}